// Round 6
// baseline (520.791 us; speedup 1.0000x reference)
//
#include <hip/hip_runtime.h>

#define N_PTS 20000
#define DIMS  128
#define A_CNT 1024
#define KNEG  10
#define NCHUNK 2512             // stride of minbuf rows (u16), chunks 0..2499 real
#define NCHUNK_REAL 2500        // 20000/8
#define BIGV  1e18f
#define CAND_CAP 768
#define PT_CAP   768

// v_sad_u8: d = c + sum_{i=0..3} |a.byte[i] - b.byte[i]|  (4 dims per VALU op)
__device__ __forceinline__ unsigned int sad_u8(unsigned int a, unsigned int b, unsigned int c) {
#if __has_builtin(__builtin_amdgcn_sad_u8)
    return __builtin_amdgcn_sad_u8(a, b, c);
#else
    unsigned int d;
    asm("v_sad_u8 %0, %1, %2, %3" : "=v"(d) : "v"(a), "v"(b), "v"(c));
    return d;
#endif
}

// ---------------------------------------------------------------------------
// absmax over both fp32 arrays (bit-pattern atomicMax valid for non-neg fp32)
// ---------------------------------------------------------------------------
__global__ void absmax_kernel(const float* __restrict__ a, const float* __restrict__ b,
                              unsigned int* __restrict__ amax) {
    const int n4 = N_PTS * DIMS / 4;
    const int stride = gridDim.x * blockDim.x;
    float m = 0.f;
    for (int i = blockIdx.x * blockDim.x + threadIdx.x; i < 2 * n4; i += stride) {
        const float4 v = (i < n4) ? ((const float4*)a)[i] : ((const float4*)b)[i - n4];
        m = fmaxf(m, fmaxf(fmaxf(fabsf(v.x), fabsf(v.y)), fmaxf(fabsf(v.z), fabsf(v.w))));
    }
#pragma unroll
    for (int s = 1; s < 64; s <<= 1) m = fmaxf(m, __shfl_xor(m, s, 64));
    if ((threadIdx.x & 63) == 0) atomicMax(amax, __float_as_uint(m));
}

// ---------------------------------------------------------------------------
// quantize q = rint(127*v/M + 127) in [0,254]; per-row residual sum
// R = sum_d |q_d - (s*v_d+127)| + 1.0 margin, and global Rmax.
// ---------------------------------------------------------------------------
__global__ void quantR_kernel(const float* __restrict__ src, unsigned int* __restrict__ dst,
                              float* __restrict__ Rrow, const unsigned int* __restrict__ amaxBits,
                              unsigned int* __restrict__ rmaxBits) {
    const int g = blockIdx.x * 256 + threadIdx.x;
    const int row = g >> 3;
    const int sub = g & 7;
    if (row >= N_PTS) return;
    const float M = __uint_as_float(*amaxBits);
    const float s = 127.0f / M;
    const float4* s4 = (const float4*)(src + (size_t)row * DIMS + sub * 16);
    unsigned int* d = dst + (size_t)row * 32 + sub * 4;
    float rs = 0.f;
#pragma unroll
    for (int m = 0; m < 4; ++m) {
        const float4 v = s4[m];
        const float f0 = v.x * s + 127.0f, f1 = v.y * s + 127.0f;
        const float f2 = v.z * s + 127.0f, f3 = v.w * s + 127.0f;
        const float q0 = rintf(f0), q1 = rintf(f1), q2 = rintf(f2), q3 = rintf(f3);
        rs += fabsf(q0 - f0) + fabsf(q1 - f1) + fabsf(q2 - f2) + fabsf(q3 - f3);
        d[m] = (unsigned int)q0 | ((unsigned int)q1 << 8) |
               ((unsigned int)q2 << 16) | ((unsigned int)q3 << 24);
    }
    rs += __shfl_xor(rs, 1, 64);
    rs += __shfl_xor(rs, 2, 64);
    rs += __shfl_xor(rs, 4, 64);
    if (sub == 0) {
        const float R = rs + 1.0f;
        Rrow[row] = R;
        atomicMax(rmaxBits, __float_as_uint(R));
    }
}

// ---------------------------------------------------------------------------
// dist kernel v2: NO LDS. Block = 4 independent waves; block covers 8 anchors
// (blockIdx.y) x 1024 points (blockIdx.x); wave w handles 4 batches of 64 pts.
// A rows: block-uniform addresses -> scalar loads (s_load_dwordx4), SGPR
// operands to v_sad_u8 (1 SGPR/VALU-instr is legal). P row: 32 VGPRs/lane,
// row-major gather cached by L1 across the 8 uint4 loads. 8 accs/lane -> no
// AGPR traffic (~60 VGPR). Round-5 4x8 LDS version was ds_read-issue-bound
// (12 b128 per 128 sads = 2x over VALU); this removes the LDS pipe entirely.
// ---------------------------------------------------------------------------
__global__ __launch_bounds__(256)
void dist_sad2(const unsigned int* __restrict__ q1, const unsigned int* __restrict__ q2,
               const int* __restrict__ anchor1, const int* __restrict__ anchor2,
               unsigned short* __restrict__ minOut) {
    const int seg  = blockIdx.x;    // 0..19 (1024 pts each)
    const int ag   = blockIdx.y;    // 0..127 (8 anchors each)
    const int side = blockIdx.z;    // 0..1

    const unsigned int* aData = side ? q2 : q1;
    const unsigned int* pData = side ? q1 : q2;
    const int*          aIdx  = side ? anchor2 : anchor1;

    const int tid = threadIdx.x;
    const int w    = tid >> 6;
    const int lane = tid & 63;

    size_t abase[8];
#pragma unroll
    for (int a = 0; a < 8; ++a) abase[a] = (size_t)aIdx[ag * 8 + a] * 32;
    const size_t outA = (size_t)side * A_CNT + ag * 8;

    for (int b = 0; b < 4; ++b) {
        const int ptBase = seg * 1024 + b * 256 + w * 64;
        const int pt  = ptBase + lane;
        const int ptc = min(pt, N_PTS - 1);
        const uint4* prow = (const uint4*)(pData + (size_t)ptc * 32);
        uint4 P[8];
#pragma unroll
        for (int m = 0; m < 8; ++m) P[m] = prow[m];
        const int cb = ptBase >> 3;

#pragma unroll
        for (int a = 0; a < 8; ++a) {
            const uint4* arow = (const uint4*)(aData + abase[a]);
            unsigned int s = 0u;
#pragma unroll
            for (int m = 0; m < 8; ++m) {
                const uint4 A = arow[m];
                s = sad_u8(A.x, P[m].x, s);
                s = sad_u8(A.y, P[m].y, s);
                s = sad_u8(A.z, P[m].z, s);
                s = sad_u8(A.w, P[m].w, s);
            }
            unsigned int mn = min(s, (unsigned int)__shfl_xor((int)s, 1, 64));
            mn = min(mn, (unsigned int)__shfl_xor((int)mn, 2, 64));
            mn = min(mn, (unsigned int)__shfl_xor((int)mn, 4, 64));
            if ((lane & 7) == 0) {
                const int cg = cb + (lane >> 3);
                if (cg < NCHUNK_REAL)
                    minOut[(outA + a) * NCHUNK + cg] = (unsigned short)mn;
            }
        }
    }
}

// ---------------------------------------------------------------------------
// select v3: one 256-thread block per (side, anchor). NO per-thread arrays
// (round-5 spilled t[10]/mv[10]/t2[10] to scratch: 110 MB WRITE_SIZE).
//  A: histogram (v>>7) of chunk-mins -> m10_ub = (b+1)<<7 >= true m10.
//  thr = m10_ub + 2*R_a + 2*Rmax + 4 (superset proof as round 5; ub only
//  widens the superset).
//  B: candidate chunks (reload minbuf, L3-resident).
//  C: per-point u8 SAD filter.
//  D: exact fp32 distances into LDS; top-10 by 10x block-argmin extraction.
// ---------------------------------------------------------------------------
__global__ __launch_bounds__(256)
void select_kernel(const float* __restrict__ out1, const float* __restrict__ out2,
                   const unsigned int* __restrict__ q1, const unsigned int* __restrict__ q2,
                   const int* __restrict__ anchor1, const int* __restrict__ anchor2,
                   const unsigned short* __restrict__ minIn,
                   const float* __restrict__ R1, const float* __restrict__ R2,
                   const unsigned int* __restrict__ rmaxBits, float* __restrict__ out) {
    const int bid = blockIdx.x;          // 0..2047
    const int side = bid >> 10;
    const int ai = bid & 1023;
    const int tid = threadIdx.x;
    const int lane = tid & 63;
    const int wv = tid >> 6;

    const float* aDataF = side ? out2 : out1;
    const float* pDataF = side ? out1 : out2;
    const unsigned int* aDataQ = side ? q2 : q1;
    const unsigned int* pDataQ = side ? q1 : q2;
    const float* Ranc = side ? R2 : R1;
    const int* aIdx = side ? anchor2 : anchor1;

    __shared__ float aRowF[DIMS];
    __shared__ unsigned int hist[256];
    __shared__ int candCount, pointCount;
    __shared__ int candList[CAND_CAP];
    __shared__ int ptList[PT_CAP];
    __shared__ float distArr[PT_CAP];
    __shared__ float sThr, sDm;
    __shared__ float wMin[4];
    __shared__ int wArg[4];

    const int arow = aIdx[ai];
    hist[tid] = 0u;
    if (tid < DIMS) aRowF[tid] = aDataF[(size_t)arow * DIMS + tid];
    const uint4 qa4 = ((const uint4*)(aDataQ + (size_t)arow * 32))[lane & 7];
    if (tid == 0) { candCount = 0; pointCount = 0; }

    if (wv == 0) {
        const int r1 = anchor1[ai], r2 = anchor2[ai];
        const float2 x1 = ((const float2*)(out1 + (size_t)r1 * DIMS))[lane];
        const float2 x2 = ((const float2*)(out2 + (size_t)r2 * DIMS))[lane];
        float dm = fabsf(x1.x - x2.x) + fabsf(x1.y - x2.y);
#pragma unroll
        for (int s = 1; s < 64; s <<= 1) dm += __shfl_xor(dm, s, 64);
        if (lane == 0) sDm = dm + 1.0f;   // GAMMA
    }
    __syncthreads();

    // Phase A: histogram of chunk minima
    const unsigned short* mbase = minIn + ((size_t)side * A_CNT + ai) * NCHUNK;
#pragma unroll
    for (int j = 0; j < 10; ++j) {
        const int c = tid + 256 * j;
        if (c < NCHUNK_REAL) {
            const unsigned int v = mbase[c];
            atomicAdd(&hist[v >> 7], 1u);
        }
    }
    __syncthreads();
    if (tid == 0) {
        unsigned int cum = 0;
        int bb = 255;
        for (int b = 0; b < 256; ++b) {
            cum += hist[b];
            if (cum >= 10u) { bb = b; break; }
        }
        const float Ra = Ranc[arow];
        const float Rm = __uint_as_float(*rmaxBits);
        sThr = (float)((bb + 1) << 7) + 2.0f * Ra + 2.0f * Rm + 4.0f;
    }
    __syncthreads();
    const float thr = sThr;

    // Phase B: candidate chunks (reload minbuf)
#pragma unroll
    for (int j = 0; j < 10; ++j) {
        const int c = tid + 256 * j;
        if (c < NCHUNK_REAL && (float)mbase[c] <= thr) {
            const int pos = atomicAdd(&candCount, 1);
            if (pos < CAND_CAP) candList[pos] = c;
        }
    }
    __syncthreads();
    const int cc = min(candCount, CAND_CAP);

    // Phase C: per-point u8 SAD filter, chunks striped over 4 waves
    const int psub = lane >> 3;
    const int segq = lane & 7;
    for (int s = wv; s < cc; s += 4) {
        const int c = candList[s];
        const int pt = c * 8 + psub;           // c < 2500 -> pt < 20000
        const uint4 qp4 = ((const uint4*)(pDataQ + (size_t)pt * 32))[segq];
        unsigned int d = sad_u8(qa4.x, qp4.x, 0u);
        d = sad_u8(qa4.y, qp4.y, d);
        d = sad_u8(qa4.z, qp4.z, d);
        d = sad_u8(qa4.w, qp4.w, d);
        int di = (int)d;
        di += __shfl_xor(di, 1, 64);
        di += __shfl_xor(di, 2, 64);
        di += __shfl_xor(di, 4, 64);
        if (segq == 0 && (float)di <= thr) {
            const int pos = atomicAdd(&pointCount, 1);
            if (pos < PT_CAP) ptList[pos] = pt;
        }
    }
    __syncthreads();
    const int pc = min(pointCount, PT_CAP);

    // Phase D: exact fp32 distances into LDS
    for (int idx = tid; idx < pc; idx += 256) {
        const int pt = ptList[idx];
        const float4* p4 = (const float4*)(pDataF + (size_t)pt * DIMS);
        float s0 = 0.f, s1 = 0.f, s2 = 0.f, s3 = 0.f;
#pragma unroll
        for (int q = 0; q < 32; ++q) {
            const float4 pvv = p4[q];
            const float4 avv = *(const float4*)&aRowF[q * 4];
            s0 += fabsf(avv.x - pvv.x);
            s1 += fabsf(avv.y - pvv.y);
            s2 += fabsf(avv.z - pvv.z);
            s3 += fabsf(avv.w - pvv.w);
        }
        distArr[idx] = (s0 + s1) + (s2 + s3);
    }
    __syncthreads();

    // top-10 by repeated block-argmin extraction (no per-thread arrays)
    float loss = 0.f;
    for (int it = 0; it < 10; ++it) {
        float lm = BIGV;
        int li = -1;
        for (int i = tid; i < pc; i += 256) {
            const float v = distArr[i];
            if (v < lm) { lm = v; li = i; }
        }
#pragma unroll
        for (int s = 1; s < 64; s <<= 1) {
            const float om = __shfl_xor(lm, s, 64);
            const int oi = __shfl_xor(li, s, 64);
            if (om < lm) { lm = om; li = oi; }
        }
        if (lane == 0) { wMin[wv] = lm; wArg[wv] = li; }
        __syncthreads();
        if (tid == 0) {
            float bm = wMin[0];
            int bi = wArg[0];
#pragma unroll
            for (int k = 1; k < 4; ++k)
                if (wMin[k] < bm) { bm = wMin[k]; bi = wArg[k]; }
            if (bi >= 0) {
                distArr[bi] = BIGV;
                loss += fmaxf(sDm - bm, 0.f);
            }
        }
        __syncthreads();
    }
    if (tid == 0) atomicAdd(out, loss * (1.0f / (A_CNT * KNEG)));
}

extern "C" void kernel_launch(void* const* d_in, const int* in_sizes, int n_in,
                              void* d_out, int out_size, void* d_ws, size_t ws_size,
                              hipStream_t stream) {
    const float* out1    = (const float*)d_in[0];
    const float* out2    = (const float*)d_in[1];
    const int*   anchor1 = (const int*)d_in[2];
    const int*   anchor2 = (const int*)d_in[3];
    float* out = (float*)d_out;

    // ws: q1 | q2 | minbuf u16 | R1 | R2 | amax | rmax  (~15.6 MB)
    unsigned int* q1 = (unsigned int*)d_ws;
    unsigned int* q2 = q1 + (size_t)N_PTS * DIMS / 4;
    unsigned short* minbuf = (unsigned short*)(q2 + (size_t)N_PTS * DIMS / 4);
    float* R1 = (float*)(minbuf + (size_t)2 * A_CNT * NCHUNK);
    float* R2 = R1 + N_PTS;
    unsigned int* amax = (unsigned int*)(R2 + N_PTS);
    unsigned int* rmax = amax + 1;

    hipMemsetAsync(out, 0, sizeof(float), stream);
    hipMemsetAsync(amax, 0, 2 * sizeof(unsigned int), stream);

    hipLaunchKernelGGL(absmax_kernel, dim3(256), dim3(256), 0, stream, out1, out2, amax);
    const int qblocks = (N_PTS * 8 + 255) / 256;
    hipLaunchKernelGGL(quantR_kernel, dim3(qblocks), dim3(256), 0, stream, out1, q1, R1, amax, rmax);
    hipLaunchKernelGGL(quantR_kernel, dim3(qblocks), dim3(256), 0, stream, out2, q2, R2, amax, rmax);

    dim3 gridA(20, 128, 2);   // 20x1024 pts covers 20000; 128x8 anchors
    hipLaunchKernelGGL(dist_sad2, gridA, dim3(256), 0, stream,
                       q1, q2, anchor1, anchor2, minbuf);
    hipLaunchKernelGGL(select_kernel, dim3(2048), dim3(256), 0, stream,
                       out1, out2, q1, q2, anchor1, anchor2, minbuf, R1, R2, rmax, out);
}

// Round 7
// 412.658 us; speedup vs baseline: 1.2620x; 1.2620x over previous
//
#include <hip/hip_runtime.h>

#define N_PTS 20000
#define DIMS  128
#define A_CNT 1024
#define KNEG  10
#define NCHUNK_REAL 2500        // 20000/8, minbuf row stride (u16)
#define BIGV  1e18f
#define CHUNK_CAP 512           // per-anchor candidate-chunk cap (E~131, +30sigma)
#define QCAP  524288            // global queue cap (E~270k)
#define SURV_CAP 320            // per-anchor surviving-point cap (E~85, +26sigma)

// v_sad_u8: d = c + sum_{i=0..3} |a.byte[i] - b.byte[i]|  (4 dims per VALU op)
__device__ __forceinline__ unsigned int sad_u8(unsigned int a, unsigned int b, unsigned int c) {
#if __has_builtin(__builtin_amdgcn_sad_u8)
    return __builtin_amdgcn_sad_u8(a, b, c);
#else
    unsigned int d;
    asm("v_sad_u8 %0, %1, %2, %3" : "=v"(d) : "v"(a), "v"(b), "v"(c));
    return d;
#endif
}

__device__ __forceinline__ void insert10f(float (&t)[10], float v) {
    if (v < t[9]) {
#pragma unroll
        for (int i = 9; i >= 1; --i) t[i] = fminf(t[i], fmaxf(t[i - 1], v));
        t[0] = fminf(t[0], v);
    }
}
__device__ __forceinline__ void mergeTop10f(float (&t)[10]) {
    for (int s = 1; s < 64; s <<= 1) {
        float o[10];
#pragma unroll
        for (int k = 0; k < 10; ++k) o[k] = __shfl_xor(t[k], s, 64);
#pragma unroll
        for (int k = 0; k < 10; ++k) insert10f(t, o[k]);
    }
}

// ---------------------------------------------------------------------------
// absmax over both fp32 arrays (bit-pattern atomicMax valid for non-neg fp32)
// ---------------------------------------------------------------------------
__global__ void absmax_kernel(const float* __restrict__ a, const float* __restrict__ b,
                              unsigned int* __restrict__ amax) {
    const int n4 = N_PTS * DIMS / 4;
    const int stride = gridDim.x * blockDim.x;
    float m = 0.f;
    for (int i = blockIdx.x * blockDim.x + threadIdx.x; i < 2 * n4; i += stride) {
        const float4 v = (i < n4) ? ((const float4*)a)[i] : ((const float4*)b)[i - n4];
        m = fmaxf(m, fmaxf(fmaxf(fabsf(v.x), fabsf(v.y)), fmaxf(fabsf(v.z), fabsf(v.w))));
    }
#pragma unroll
    for (int s = 1; s < 64; s <<= 1) m = fmaxf(m, __shfl_xor(m, s, 64));
    if ((threadIdx.x & 63) == 0) atomicMax(amax, __float_as_uint(m));
}

// ---------------------------------------------------------------------------
// quantize q = rint(127*v/M + 127) in [0,254]; per-row residual sum
// R = sum_d |q_d - (s*v_d+127)| + 1.0 margin, and global Rmax.
// ---------------------------------------------------------------------------
__global__ void quantR_kernel(const float* __restrict__ src, unsigned int* __restrict__ dst,
                              float* __restrict__ Rrow, const unsigned int* __restrict__ amaxBits,
                              unsigned int* __restrict__ rmaxBits) {
    const int g = blockIdx.x * 256 + threadIdx.x;
    const int row = g >> 3;
    const int sub = g & 7;
    if (row >= N_PTS) return;
    const float M = __uint_as_float(*amaxBits);
    const float s = 127.0f / M;
    const float4* s4 = (const float4*)(src + (size_t)row * DIMS + sub * 16);
    unsigned int* d = dst + (size_t)row * 32 + sub * 4;
    float rs = 0.f;
#pragma unroll
    for (int m = 0; m < 4; ++m) {
        const float4 v = s4[m];
        const float f0 = v.x * s + 127.0f, f1 = v.y * s + 127.0f;
        const float f2 = v.z * s + 127.0f, f3 = v.w * s + 127.0f;
        const float q0 = rintf(f0), q1 = rintf(f1), q2 = rintf(f2), q3 = rintf(f3);
        rs += fabsf(q0 - f0) + fabsf(q1 - f1) + fabsf(q2 - f2) + fabsf(q3 - f3);
        d[m] = (unsigned int)q0 | ((unsigned int)q1 << 8) |
               ((unsigned int)q2 << 16) | ((unsigned int)q3 << 24);
    }
    rs += __shfl_xor(rs, 1, 64);
    rs += __shfl_xor(rs, 2, 64);
    rs += __shfl_xor(rs, 4, 64);
    if (sub == 0) {
        const float R = rs + 1.0f;
        Rrow[row] = R;
        atomicMax(rmaxBits, __float_as_uint(R));
    }
}

// ---------------------------------------------------------------------------
// dist_sad3: block = 256 pts (one row per thread, loaded ONCE) x 128 anchors.
// A rows stream through the scalar pipe: readfirstlane-forced uniform row
// index -> s_load, SGPR src0 into v_sad_u8 (legal: 1 SGPR per VALU instr).
// No LDS. Round-6 version re-gathered P per 8 anchors (128x redundant,
// ~67us of divergent-address cycles); this loads P once per block.
// ---------------------------------------------------------------------------
__global__ __launch_bounds__(256)
void dist_sad3(const unsigned int* __restrict__ q1, const unsigned int* __restrict__ q2,
               const int* __restrict__ anchor1, const int* __restrict__ anchor2,
               unsigned short* __restrict__ minOut) {
    const int pb   = blockIdx.x;          // 0..78 (256 pts each)
    const int ag   = blockIdx.y;          // 0..7  (128 anchors each)
    const int side = blockIdx.z;          // 0..1

    const unsigned int* aData = side ? q2 : q1;
    const unsigned int* pData = side ? q1 : q2;
    const int* aIdx = side ? anchor2 : anchor1;

    const int tid  = threadIdx.x;
    const int lane = tid & 63;
    const int pt   = pb * 256 + tid;
    const int ptc  = min(pt, N_PTS - 1);

    uint4 P[8];
    {
        const uint4* prow = (const uint4*)(pData + (size_t)ptc * 32);
#pragma unroll
        for (int m = 0; m < 8; ++m) P[m] = prow[m];
    }

    const int chunk = pt >> 3;
    const bool doStore = ((lane & 7) == 0) && (pt < N_PTS);
    unsigned short* obase = minOut + (size_t)(side * A_CNT + ag * 128) * NCHUNK_REAL + chunk;

#pragma unroll 2
    for (int a = 0; a < 128; ++a) {
        const int arow = __builtin_amdgcn_readfirstlane(aIdx[ag * 128 + a]);
        const uint4* a4 = (const uint4*)(aData + (size_t)arow * 32);
        unsigned int s = 0u;
#pragma unroll
        for (int m = 0; m < 8; ++m) {
            const uint4 A = a4[m];
            s = sad_u8(A.x, P[m].x, s);
            s = sad_u8(A.y, P[m].y, s);
            s = sad_u8(A.z, P[m].z, s);
            s = sad_u8(A.w, P[m].w, s);
        }
        unsigned int mn = min(s, (unsigned int)__shfl_xor((int)s, 1, 64));
        mn = min(mn, (unsigned int)__shfl_xor((int)mn, 2, 64));
        mn = min(mn, (unsigned int)__shfl_xor((int)mn, 4, 64));
        if (doStore) obase[(size_t)a * NCHUNK_REAL] = (unsigned short)mn;
    }
}

// ---------------------------------------------------------------------------
// select1: one block per (side, anchor). m10 upper bound via 32-int-bucket
// LDS histogram + wave-parallel prefix scan (round-6's tid0 serial scan was
// ~4us/block). Emits candidate chunks (min <= thrChunk) to a GLOBAL queue and
// per-anchor point threshold thrPt = m10ub + 2Ra + Rmax + 4 (pointwise +Rp
// added in select2 — tighter than round 6's 2Rmax global slack).
// ---------------------------------------------------------------------------
__global__ __launch_bounds__(256)
void select1(const unsigned short* __restrict__ minIn,
             const int* __restrict__ anchor1, const int* __restrict__ anchor2,
             const float* __restrict__ R1, const float* __restrict__ R2,
             const unsigned int* __restrict__ rmaxBits,
             float* __restrict__ thrPt, unsigned int* __restrict__ queue,
             unsigned int* __restrict__ qCount) {
    const int bid = blockIdx.x;
    const int side = bid >> 10;
    const int ai = bid & 1023;
    const int tid = threadIdx.x;

    __shared__ unsigned int hist[512];
    __shared__ int cList[CHUNK_CAP];
    __shared__ int cNum, sBase;
    __shared__ float sM10;

    hist[tid] = 0u; hist[tid + 256] = 0u;
    if (tid == 0) cNum = 0;
    const int* aIdx = side ? anchor2 : anchor1;
    const float* Ranc = side ? R2 : R1;
    const int arow = aIdx[ai];
    __syncthreads();

    const unsigned short* mbase = minIn + (size_t)(side * A_CNT + ai) * NCHUNK_REAL;
    unsigned int v[10];
#pragma unroll
    for (int j = 0; j < 10; ++j) {
        const int c = tid + 256 * j;
        v[j] = 0xFFFFFFFFu;
        if (c < NCHUNK_REAL) {
            v[j] = mbase[c];
            atomicAdd(&hist[min(v[j] >> 5, 511u)], 1u);
        }
    }
    __syncthreads();

    if (tid < 64) {
        unsigned int carry = 0;
        int found = 0;
        for (int r = 0; r < 8; ++r) {
            unsigned int sc = hist[r * 64 + tid];
#pragma unroll
            for (int s = 1; s < 64; s <<= 1) {
                const unsigned int o = __shfl_up(sc, s, 64);
                if (tid >= s) sc += o;
            }
            const unsigned long long bal = __ballot(carry + sc >= 10u);
            if (!found && bal) {
                const int b = __ffsll((unsigned long long)bal) - 1;
                if (tid == 0) sM10 = (float)((r * 64 + b + 1) << 5);
                found = 1;
            }
            carry += __shfl(sc, 63, 64);
        }
        if (!found && tid == 0) sM10 = 65535.f;   // unreachable for this data
    }
    __syncthreads();

    const float Ra = Ranc[arow];
    const float Rm = __uint_as_float(*rmaxBits);
    const float thrC = sM10 + 2.f * Ra + 2.f * Rm + 4.f;
    if (tid == 0) thrPt[side * A_CNT + ai] = sM10 + 2.f * Ra + Rm + 4.f;

#pragma unroll
    for (int j = 0; j < 10; ++j) {
        const int c = tid + 256 * j;
        if (c < NCHUNK_REAL && (float)v[j] <= thrC) {
            const int pos = atomicAdd(&cNum, 1);
            if (pos < CHUNK_CAP) cList[pos] = c;
        }
    }
    __syncthreads();
    const int n = min(cNum, CHUNK_CAP);
    if (tid == 0) sBase = (int)atomicAdd(qCount, (unsigned int)n);
    __syncthreads();
    const unsigned int tag = (unsigned int)(side * A_CNT + ai) << 12;
    for (int i = tid; i < n; i += 256) {
        const int q = sBase + i;
        if (q < QCAP) queue[q] = tag | (unsigned int)cList[i];
    }
}

// ---------------------------------------------------------------------------
// select2: ONE WAVE PER QUEUE ENTRY (side,anchor,chunk) — ~270k waves, fully
// latency-hidden (round 6 looped candidates serially inside each block).
// 64 lanes = 8 pts x 8 segs: u8 SAD -> pointwise filter d_int <= thrPt+Rp ->
// each passing pt: exact fp32 L1 (coalesced 512B row, wave-reduce) appended
// to the per-anchor survivor buffer.
// ---------------------------------------------------------------------------
__global__ __launch_bounds__(256)
void select2(const float* __restrict__ out1, const float* __restrict__ out2,
             const unsigned int* __restrict__ q1, const unsigned int* __restrict__ q2,
             const int* __restrict__ anchor1, const int* __restrict__ anchor2,
             const float* __restrict__ R1, const float* __restrict__ R2,
             const float* __restrict__ thrPt, const unsigned int* __restrict__ queue,
             const unsigned int* __restrict__ qCount,
             float* __restrict__ survDist, unsigned int* __restrict__ survCnt) {
    const int tid = threadIdx.x;
    const int lane = tid & 63;
    const unsigned int wid = (blockIdx.x * 256 + tid) >> 6;
    const unsigned int nw = gridDim.x * 4;
    const unsigned int qn = min(*qCount, (unsigned int)QCAP);

    for (unsigned int e = wid; e < qn; e += nw) {
        const unsigned int ent = queue[e];
        const int sa = (int)(ent >> 12);
        const int chunk = (int)(ent & 0xFFFu);
        const int side = sa >> 10;
        const int ai = sa & 1023;
        const int* aIdx = side ? anchor2 : anchor1;
        const unsigned int* aQ = side ? q2 : q1;
        const unsigned int* pQ = side ? q1 : q2;
        const float* aF = side ? out2 : out1;
        const float* pF = side ? out1 : out2;
        const float* Rp = side ? R1 : R2;       // residuals of the P side

        const int arow = __builtin_amdgcn_readfirstlane(aIdx[ai]);
        const int pt  = chunk * 8 + (lane >> 3);
        const int seg = lane & 7;
        const uint4 qa = ((const uint4*)(aQ + (size_t)arow * 32))[seg];
        const uint4 qp = ((const uint4*)(pQ + (size_t)pt * 32))[seg];
        unsigned int d = sad_u8(qa.x, qp.x, 0u);
        d = sad_u8(qa.y, qp.y, d);
        d = sad_u8(qa.z, qp.z, d);
        d = sad_u8(qa.w, qp.w, d);
        int di = (int)d;
        di += __shfl_xor(di, 1, 64);
        di += __shfl_xor(di, 2, 64);
        di += __shfl_xor(di, 4, 64);
        const bool pass = (seg == 0) && ((float)di <= thrPt[sa] + Rp[pt]);
        unsigned long long mask = __ballot(pass);

        const float2 av = ((const float2*)(aF + (size_t)arow * DIMS))[lane];
        while (mask) {
            const int src = __ffsll(mask) - 1;
            mask &= mask - 1;
            const int ptb = chunk * 8 + (src >> 3);
            const float2 pv = ((const float2*)(pF + (size_t)ptb * DIMS))[lane];
            float s = fabsf(av.x - pv.x) + fabsf(av.y - pv.y);
#pragma unroll
            for (int t = 1; t < 64; t <<= 1) s += __shfl_xor(s, t, 64);
            if (lane == 0) {
                const unsigned int pos = atomicAdd(&survCnt[sa], 1u);
                if (pos < SURV_CAP) survDist[(size_t)sa * SURV_CAP + pos] = s;
            }
        }
    }
}

// ---------------------------------------------------------------------------
// select3: one wave per (side, anchor): top-10 of the survivor list (lean
// kernel — t[10] stays in VGPRs, no spill), Dm, loss, one atomicAdd.
// ---------------------------------------------------------------------------
__global__ __launch_bounds__(256)
void select3(const float* __restrict__ out1, const float* __restrict__ out2,
             const int* __restrict__ anchor1, const int* __restrict__ anchor2,
             const float* __restrict__ survDist, const unsigned int* __restrict__ survCnt,
             float* __restrict__ out) {
    const int tid = threadIdx.x;
    const int lane = tid & 63;
    const int sa = blockIdx.x * 4 + (tid >> 6);   // 0..2047
    const int ai = sa & 1023;

    const int r1 = anchor1[ai], r2 = anchor2[ai];
    const float2 x1 = ((const float2*)(out1 + (size_t)r1 * DIMS))[lane];
    const float2 x2 = ((const float2*)(out2 + (size_t)r2 * DIMS))[lane];
    float dm = fabsf(x1.x - x2.x) + fabsf(x1.y - x2.y);
#pragma unroll
    for (int s = 1; s < 64; s <<= 1) dm += __shfl_xor(dm, s, 64);
    dm += 1.0f;   // GAMMA

    const unsigned int n = min(survCnt[sa], (unsigned int)SURV_CAP);
    float t[10];
#pragma unroll
    for (int k = 0; k < 10; ++k) t[k] = BIGV;
    const float* dv = survDist + (size_t)sa * SURV_CAP;
    for (unsigned int i = lane; i < n; i += 64) insert10f(t, dv[i]);
    mergeTop10f(t);

    if (lane == 0) {
        float sum = 0.f;
#pragma unroll
        for (int k = 0; k < 10; ++k) sum += fmaxf(dm - t[k], 0.f);
        atomicAdd(out, sum * (1.0f / (A_CNT * KNEG)));
    }
}

extern "C" void kernel_launch(void* const* d_in, const int* in_sizes, int n_in,
                              void* d_out, int out_size, void* d_ws, size_t ws_size,
                              hipStream_t stream) {
    const float* out1    = (const float*)d_in[0];
    const float* out2    = (const float*)d_in[1];
    const int*   anchor1 = (const int*)d_in[2];
    const int*   anchor2 = (const int*)d_in[3];
    float* out = (float*)d_out;

    // ws layout (~20.25 MB total, <= 20.58 MB proven in round 1)
    unsigned int* q1 = (unsigned int*)d_ws;                         // 640000 u32
    unsigned int* q2 = q1 + 640000;                                 // 640000 u32
    unsigned short* minbuf = (unsigned short*)(q2 + 640000);        // 2*1024*2500 u16
    float* R1 = (float*)(minbuf + (size_t)2 * A_CNT * NCHUNK_REAL); // 20000
    float* R2 = R1 + N_PTS;                                         // 20000
    float* thrPt = R2 + N_PTS;                                      // 2048
    float* survDist = thrPt + 2048;                                 // 2048*320
    unsigned int* queue = (unsigned int*)(survDist + 2048 * SURV_CAP); // QCAP
    unsigned int* survCnt = queue + QCAP;                           // 2048
    unsigned int* qCnt = survCnt + 2048;                            // 1
    unsigned int* amax = qCnt + 1;                                  // 1
    unsigned int* rmax = amax + 1;                                  // 1

    hipMemsetAsync(out, 0, sizeof(float), stream);
    hipMemsetAsync(survCnt, 0, (2048 + 3) * sizeof(unsigned int), stream);

    hipLaunchKernelGGL(absmax_kernel, dim3(256), dim3(256), 0, stream, out1, out2, amax);
    const int qblocks = (N_PTS * 8 + 255) / 256;
    hipLaunchKernelGGL(quantR_kernel, dim3(qblocks), dim3(256), 0, stream, out1, q1, R1, amax, rmax);
    hipLaunchKernelGGL(quantR_kernel, dim3(qblocks), dim3(256), 0, stream, out2, q2, R2, amax, rmax);

    hipLaunchKernelGGL(dist_sad3, dim3(79, 8, 2), dim3(256), 0, stream,
                       q1, q2, anchor1, anchor2, minbuf);
    hipLaunchKernelGGL(select1, dim3(2048), dim3(256), 0, stream,
                       minbuf, anchor1, anchor2, R1, R2, rmax, thrPt, queue, qCnt);
    hipLaunchKernelGGL(select2, dim3(4096), dim3(256), 0, stream,
                       out1, out2, q1, q2, anchor1, anchor2, R1, R2,
                       thrPt, queue, qCnt, survDist, survCnt);
    hipLaunchKernelGGL(select3, dim3(512), dim3(256), 0, stream,
                       out1, out2, anchor1, anchor2, survDist, survCnt, out);
}

// Round 8
// 377.795 us; speedup vs baseline: 1.3785x; 1.0923x over previous
//
#include <hip/hip_runtime.h>

#define N_PTS 20000
#define DIMS  128
#define A_CNT 1024
#define KNEG  10
#define NCHUNK_REAL 2500        // 20000/8, minbuf row stride (u16)
#define BIGV  1e18f
#define CHUNK_CAP 512           // per-anchor candidate-chunk cap (E~95)
#define QCAP  393216            // global chunk-queue cap (E~195k)
#define SURV_CAP 320            // per-anchor surviving-point cap (E~65)

// v_sad_u8: d = c + sum_{i=0..3} |a.byte[i] - b.byte[i]|  (4 dims per VALU op)
__device__ __forceinline__ unsigned int sad_u8(unsigned int a, unsigned int b, unsigned int c) {
#if __has_builtin(__builtin_amdgcn_sad_u8)
    return __builtin_amdgcn_sad_u8(a, b, c);
#else
    unsigned int d;
    asm("v_sad_u8 %0, %1, %2, %3" : "=v"(d) : "v"(a), "v"(b), "v"(c));
    return d;
#endif
}

__device__ __forceinline__ void insert10f(float (&t)[10], float v) {
    if (v < t[9]) {
#pragma unroll
        for (int i = 9; i >= 1; --i) t[i] = fminf(t[i], fmaxf(t[i - 1], v));
        t[0] = fminf(t[0], v);
    }
}
__device__ __forceinline__ void mergeTop10f(float (&t)[10]) {
    for (int s = 1; s < 64; s <<= 1) {
        float o[10];
#pragma unroll
        for (int k = 0; k < 10; ++k) o[k] = __shfl_xor(t[k], s, 64);
#pragma unroll
        for (int k = 0; k < 10; ++k) insert10f(t, o[k]);
    }
}

// ---------------------------------------------------------------------------
// absmax over both fp32 arrays (bit-pattern atomicMax valid for non-neg fp32)
// ---------------------------------------------------------------------------
__global__ void absmax_kernel(const float* __restrict__ a, const float* __restrict__ b,
                              unsigned int* __restrict__ amax) {
    const int n4 = N_PTS * DIMS / 4;
    const int stride = gridDim.x * blockDim.x;
    float m = 0.f;
    for (int i = blockIdx.x * blockDim.x + threadIdx.x; i < 2 * n4; i += stride) {
        const float4 v = (i < n4) ? ((const float4*)a)[i] : ((const float4*)b)[i - n4];
        m = fmaxf(m, fmaxf(fmaxf(fabsf(v.x), fabsf(v.y)), fmaxf(fabsf(v.z), fabsf(v.w))));
    }
#pragma unroll
    for (int s = 1; s < 64; s <<= 1) m = fmaxf(m, __shfl_xor(m, s, 64));
    if ((threadIdx.x & 63) == 0) atomicMax(amax, __float_as_uint(m));
}

// ---------------------------------------------------------------------------
// quantize q = rint(127*v/M + 127) in [0,254]; per-row residual sum
// R = sum_d |q_d - (s*v_d+127)| + 1.0 margin, and global Rmax.
// ---------------------------------------------------------------------------
__global__ void quantR_kernel(const float* __restrict__ src, unsigned int* __restrict__ dst,
                              float* __restrict__ Rrow, const unsigned int* __restrict__ amaxBits,
                              unsigned int* __restrict__ rmaxBits) {
    const int g = blockIdx.x * 256 + threadIdx.x;
    const int row = g >> 3;
    const int sub = g & 7;
    if (row >= N_PTS) return;
    const float M = __uint_as_float(*amaxBits);
    const float s = 127.0f / M;
    const float4* s4 = (const float4*)(src + (size_t)row * DIMS + sub * 16);
    unsigned int* d = dst + (size_t)row * 32 + sub * 4;
    float rs = 0.f;
#pragma unroll
    for (int m = 0; m < 4; ++m) {
        const float4 v = s4[m];
        const float f0 = v.x * s + 127.0f, f1 = v.y * s + 127.0f;
        const float f2 = v.z * s + 127.0f, f3 = v.w * s + 127.0f;
        const float q0 = rintf(f0), q1 = rintf(f1), q2 = rintf(f2), q3 = rintf(f3);
        rs += fabsf(q0 - f0) + fabsf(q1 - f1) + fabsf(q2 - f2) + fabsf(q3 - f3);
        d[m] = (unsigned int)q0 | ((unsigned int)q1 << 8) |
               ((unsigned int)q2 << 16) | ((unsigned int)q3 << 24);
    }
    rs += __shfl_xor(rs, 1, 64);
    rs += __shfl_xor(rs, 2, 64);
    rs += __shfl_xor(rs, 4, 64);
    if (sub == 0) {
        const float R = rs + 1.0f;
        Rrow[row] = R;
        atomicMax(rmaxBits, __float_as_uint(R));
    }
}

// ---------------------------------------------------------------------------
// dist_sad3: block = 256 pts (one row per thread, loaded ONCE) x 128 anchors.
// A rows via scalar pipe (readfirstlane -> s_load, SGPR src into v_sad_u8).
// No LDS. (unchanged from round 7 — its true cost surfaces this round)
// ---------------------------------------------------------------------------
__global__ __launch_bounds__(256)
void dist_sad3(const unsigned int* __restrict__ q1, const unsigned int* __restrict__ q2,
               const int* __restrict__ anchor1, const int* __restrict__ anchor2,
               unsigned short* __restrict__ minOut) {
    const int pb   = blockIdx.x;          // 0..78 (256 pts each)
    const int ag   = blockIdx.y;          // 0..7  (128 anchors each)
    const int side = blockIdx.z;          // 0..1

    const unsigned int* aData = side ? q2 : q1;
    const unsigned int* pData = side ? q1 : q2;
    const int* aIdx = side ? anchor2 : anchor1;

    const int tid  = threadIdx.x;
    const int lane = tid & 63;
    const int pt   = pb * 256 + tid;
    const int ptc  = min(pt, N_PTS - 1);

    uint4 P[8];
    {
        const uint4* prow = (const uint4*)(pData + (size_t)ptc * 32);
#pragma unroll
        for (int m = 0; m < 8; ++m) P[m] = prow[m];
    }

    const int chunk = pt >> 3;
    const bool doStore = ((lane & 7) == 0) && (pt < N_PTS);
    unsigned short* obase = minOut + (size_t)(side * A_CNT + ag * 128) * NCHUNK_REAL + chunk;

#pragma unroll 2
    for (int a = 0; a < 128; ++a) {
        const int arow = __builtin_amdgcn_readfirstlane(aIdx[ag * 128 + a]);
        const uint4* a4 = (const uint4*)(aData + (size_t)arow * 32);
        unsigned int s = 0u;
#pragma unroll
        for (int m = 0; m < 8; ++m) {
            const uint4 A = a4[m];
            s = sad_u8(A.x, P[m].x, s);
            s = sad_u8(A.y, P[m].y, s);
            s = sad_u8(A.z, P[m].z, s);
            s = sad_u8(A.w, P[m].w, s);
        }
        unsigned int mn = min(s, (unsigned int)__shfl_xor((int)s, 1, 64));
        mn = min(mn, (unsigned int)__shfl_xor((int)mn, 2, 64));
        mn = min(mn, (unsigned int)__shfl_xor((int)mn, 4, 64));
        if (doStore) obase[(size_t)a * NCHUNK_REAL] = (unsigned short)mn;
    }
}

// ---------------------------------------------------------------------------
// select1 v2: one block per (side, anchor). m10 upper bound via BLOCK-WIDE
// BINARY SEARCH (11 iters over [0,32768) -> slack <= 16; round-7 histogram
// funneled 2500 LDS atomics into ~8 hot buckets = serialization). Emits
// candidate chunks (min <= thrC) to the global queue + per-anchor thrPt.
// ---------------------------------------------------------------------------
__global__ __launch_bounds__(256)
void select1(const unsigned short* __restrict__ minIn,
             const int* __restrict__ anchor1, const int* __restrict__ anchor2,
             const float* __restrict__ R1, const float* __restrict__ R2,
             const unsigned int* __restrict__ rmaxBits,
             float* __restrict__ thrPt, unsigned int* __restrict__ queue,
             unsigned int* __restrict__ qCount) {
    const int bid = blockIdx.x;
    const int side = bid >> 10;
    const int ai = bid & 1023;
    const int tid = threadIdx.x;
    const int lane = tid & 63;

    __shared__ int sCnt;
    __shared__ int cList[CHUNK_CAP];
    __shared__ int cNum, sBase;

    if (tid == 0) cNum = 0;
    const int* aIdx = side ? anchor2 : anchor1;
    const float* Ranc = side ? R2 : R1;
    const int arow = aIdx[ai];

    const unsigned short* mbase = minIn + (size_t)(side * A_CNT + ai) * NCHUNK_REAL;
    int v[10];
#pragma unroll
    for (int j = 0; j < 10; ++j) {
        const int c = tid + 256 * j;
        v[j] = (c < NCHUNK_REAL) ? (int)mbase[c] : 0x7FFF;
    }

    // block-wide binary search for smallest T (mult of 16) with count(<=T) >= 10
    int lo = 0, hi = 32768;
    while (hi - lo > 16) {
        const int mid = (lo + hi) >> 1;
        int c = 0;
#pragma unroll
        for (int j = 0; j < 10; ++j) c += (v[j] <= mid);
#pragma unroll
        for (int s = 1; s < 64; s <<= 1) c += __shfl_xor(c, s, 64);
        if (tid == 0) sCnt = 0;
        __syncthreads();
        if (lane == 0) atomicAdd(&sCnt, c);
        __syncthreads();
        if (sCnt >= 10) hi = mid; else lo = mid;
    }
    const float m10ub = (float)hi;

    const float Ra = Ranc[arow];
    const float Rm = __uint_as_float(*rmaxBits);
    const float thrC = m10ub + 2.f * Ra + 2.f * Rm + 4.f;
    if (tid == 0) thrPt[side * A_CNT + ai] = m10ub + 2.f * Ra + Rm + 4.f;

#pragma unroll
    for (int j = 0; j < 10; ++j) {
        const int c = tid + 256 * j;
        if (c < NCHUNK_REAL && (float)v[j] <= thrC) {
            const int pos = atomicAdd(&cNum, 1);
            if (pos < CHUNK_CAP) cList[pos] = c;
        }
    }
    __syncthreads();
    const int n = min(cNum, CHUNK_CAP);
    if (tid == 0) sBase = (int)atomicAdd(qCount, (unsigned int)n);
    __syncthreads();
    const unsigned int tag = (unsigned int)(side * A_CNT + ai) << 12;
    for (int i = tid; i < n; i += 256) {
        const int q = sBase + i;
        if (q < QCAP) queue[q] = tag | (unsigned int)cList[i];
    }
}

// ---------------------------------------------------------------------------
// select2 v2: PURE u8 filter — no fp32 loads (round 7 fetched the 512B fp32
// anchor row per entry = 97 of its 100 MB FETCH). One wave per queue entry,
// contiguous entry runs per wave (same-anchor locality). Survivor points
// appended to per-anchor survPt lists.
// ---------------------------------------------------------------------------
__global__ __launch_bounds__(256)
void select2(const unsigned int* __restrict__ q1, const unsigned int* __restrict__ q2,
             const int* __restrict__ anchor1, const int* __restrict__ anchor2,
             const float* __restrict__ R1, const float* __restrict__ R2,
             const float* __restrict__ thrPt, const unsigned int* __restrict__ queue,
             const unsigned int* __restrict__ qCount,
             unsigned short* __restrict__ survPt, unsigned int* __restrict__ survCnt) {
    const int tid = threadIdx.x;
    const int lane = tid & 63;
    const unsigned int wid = (blockIdx.x * 256 + tid) >> 6;
    const unsigned int nw = gridDim.x * 4;
    const unsigned int qn = min(*qCount, (unsigned int)QCAP);
    const unsigned int per = (qn + nw - 1) / nw;
    const unsigned int e0 = wid * per;
    const unsigned int e1 = min(qn, e0 + per);

    const int psub = lane >> 3;
    const int seg  = lane & 7;

    for (unsigned int e = e0; e < e1; ++e) {
        const unsigned int ent = queue[e];
        const int sa = (int)(ent >> 12);
        const int chunk = (int)(ent & 0xFFFu);
        const int side = sa >> 10;
        const int ai = sa & 1023;
        const int* aIdx = side ? anchor2 : anchor1;
        const unsigned int* aQ = side ? q2 : q1;
        const unsigned int* pQ = side ? q1 : q2;
        const float* Rp = side ? R1 : R2;       // residuals of the P side

        const int arow = __builtin_amdgcn_readfirstlane(aIdx[ai]);
        const int pt = chunk * 8 + psub;
        const uint4 qa = ((const uint4*)(aQ + (size_t)arow * 32))[seg];
        const uint4 qp = ((const uint4*)(pQ + (size_t)pt * 32))[seg];
        unsigned int d = sad_u8(qa.x, qp.x, 0u);
        d = sad_u8(qa.y, qp.y, d);
        d = sad_u8(qa.z, qp.z, d);
        d = sad_u8(qa.w, qp.w, d);
        int di = (int)d;
        di += __shfl_xor(di, 1, 64);
        di += __shfl_xor(di, 2, 64);
        di += __shfl_xor(di, 4, 64);
        if (seg == 0 && (float)di <= thrPt[sa] + Rp[pt]) {
            const unsigned int pos = atomicAdd(&survCnt[sa], 1u);
            if (pos < SURV_CAP) survPt[(size_t)sa * SURV_CAP + pos] = (unsigned short)pt;
        }
    }
}

// ---------------------------------------------------------------------------
// select3 v2: one block per (side, anchor). Anchor fp32 row staged once in
// LDS; each wave computes exact L1 for survivors (coalesced 512B row reads);
// wave 0 then top-10s the <=320 distances, adds Dm-margin loss.
// ---------------------------------------------------------------------------
__global__ __launch_bounds__(256)
void select3(const float* __restrict__ out1, const float* __restrict__ out2,
             const int* __restrict__ anchor1, const int* __restrict__ anchor2,
             const unsigned short* __restrict__ survPt, const unsigned int* __restrict__ survCnt,
             float* __restrict__ out) {
    const int sa = blockIdx.x;           // 0..2047
    const int side = sa >> 10;
    const int ai = sa & 1023;
    const int tid = threadIdx.x;
    const int lane = tid & 63;
    const int wv = tid >> 6;

    const float* aF = side ? out2 : out1;
    const float* pF = side ? out1 : out2;
    const int* aIdx = side ? anchor2 : anchor1;

    __shared__ float aRowF[DIMS];
    __shared__ float distArr[SURV_CAP];
    __shared__ float sDm;

    const int arow = aIdx[ai];
    if (tid < DIMS) aRowF[tid] = aF[(size_t)arow * DIMS + tid];

    if (wv == 1) {   // Dm in parallel with staging
        const int r1 = anchor1[ai], r2 = anchor2[ai];
        const float2 x1 = ((const float2*)(out1 + (size_t)r1 * DIMS))[lane];
        const float2 x2 = ((const float2*)(out2 + (size_t)r2 * DIMS))[lane];
        float dm = fabsf(x1.x - x2.x) + fabsf(x1.y - x2.y);
#pragma unroll
        for (int s = 1; s < 64; s <<= 1) dm += __shfl_xor(dm, s, 64);
        if (lane == 0) sDm = dm + 1.0f;   // GAMMA
    }
    __syncthreads();

    const int n = (int)min(survCnt[sa], (unsigned int)SURV_CAP);
    for (int idx = wv; idx < n; idx += 4) {
        const int pt = survPt[(size_t)sa * SURV_CAP + idx];
        const float2 pv = ((const float2*)(pF + (size_t)pt * DIMS))[lane];
        const float2 av = *(const float2*)&aRowF[2 * lane];
        float s = fabsf(av.x - pv.x) + fabsf(av.y - pv.y);
#pragma unroll
        for (int t = 1; t < 64; t <<= 1) s += __shfl_xor(s, t, 64);
        if (lane == 0) distArr[idx] = s;
    }
    __syncthreads();

    if (wv == 0) {
        float t[10];
#pragma unroll
        for (int k = 0; k < 10; ++k) t[k] = BIGV;
#pragma unroll
        for (int j = 0; j < 5; ++j) {
            const int i = lane + 64 * j;
            if (i < n) insert10f(t, distArr[i]);
        }
        mergeTop10f(t);
        if (lane == 0) {
            const float dm = sDm;
            float sum = 0.f;
#pragma unroll
            for (int k = 0; k < 10; ++k) sum += fmaxf(dm - t[k], 0.f);
            atomicAdd(out, sum * (1.0f / (A_CNT * KNEG)));
        }
    }
}

extern "C" void kernel_launch(void* const* d_in, const int* in_sizes, int n_in,
                              void* d_out, int out_size, void* d_ws, size_t ws_size,
                              hipStream_t stream) {
    const float* out1    = (const float*)d_in[0];
    const float* out2    = (const float*)d_in[1];
    const int*   anchor1 = (const int*)d_in[2];
    const int*   anchor2 = (const int*)d_in[3];
    float* out = (float*)d_out;

    // ws layout (~18.4 MB)
    unsigned int* q1 = (unsigned int*)d_ws;                         // 640000 u32
    unsigned int* q2 = q1 + 640000;                                 // 640000 u32
    unsigned short* minbuf = (unsigned short*)(q2 + 640000);        // 2048*2500 u16
    float* R1 = (float*)(minbuf + (size_t)2 * A_CNT * NCHUNK_REAL); // 20000
    float* R2 = R1 + N_PTS;                                         // 20000
    float* thrPt = R2 + N_PTS;                                      // 2048
    unsigned short* survPt = (unsigned short*)(thrPt + 2048);       // 2048*320 u16
    unsigned int* queue = (unsigned int*)(survPt + (size_t)2048 * SURV_CAP); // QCAP
    unsigned int* survCnt = queue + QCAP;                           // 2048
    unsigned int* qCnt = survCnt + 2048;                            // 1
    unsigned int* amax = qCnt + 1;                                  // 1
    unsigned int* rmax = amax + 1;                                  // 1

    hipMemsetAsync(out, 0, sizeof(float), stream);
    hipMemsetAsync(survCnt, 0, (2048 + 3) * sizeof(unsigned int), stream);

    hipLaunchKernelGGL(absmax_kernel, dim3(256), dim3(256), 0, stream, out1, out2, amax);
    const int qblocks = (N_PTS * 8 + 255) / 256;
    hipLaunchKernelGGL(quantR_kernel, dim3(qblocks), dim3(256), 0, stream, out1, q1, R1, amax, rmax);
    hipLaunchKernelGGL(quantR_kernel, dim3(qblocks), dim3(256), 0, stream, out2, q2, R2, amax, rmax);

    hipLaunchKernelGGL(dist_sad3, dim3(79, 8, 2), dim3(256), 0, stream,
                       q1, q2, anchor1, anchor2, minbuf);
    hipLaunchKernelGGL(select1, dim3(2048), dim3(256), 0, stream,
                       minbuf, anchor1, anchor2, R1, R2, rmax, thrPt, queue, qCnt);
    hipLaunchKernelGGL(select2, dim3(2048), dim3(256), 0, stream,
                       q1, q2, anchor1, anchor2, R1, R2, thrPt, queue, qCnt, survPt, survCnt);
    hipLaunchKernelGGL(select3, dim3(2048), dim3(256), 0, stream,
                       out1, out2, anchor1, anchor2, survPt, survCnt, out);
}